// Round 1
// baseline (302.825 us; speedup 1.0000x reference)
//
#include <hip/hip_runtime.h>
#include <hip/hip_bf16.h>

typedef short v8s __attribute__((ext_vector_type(8)));
typedef float v4f __attribute__((ext_vector_type(4)));
typedef __hip_bfloat16 bf16;

#define MFMA(a, b, c) __builtin_amdgcn_mfma_f32_16x16x32_bf16(a, b, c, 0, 0, 0)

// ---------------------------------------------------------------------------
// All fp32->bf16 casts in ONE launch. grid=(4096,6); region r sized n4 vec4s.
// ---------------------------------------------------------------------------
__global__ __launch_bounds__(256) void cast_all(
    const float* __restrict__ x,  const float* __restrict__ wq,
    const float* __restrict__ wk, const float* __restrict__ wv,
    const float* __restrict__ wo, const float* __restrict__ er,
    bf16* __restrict__ xb,  bf16* __restrict__ wqb, bf16* __restrict__ wkb,
    bf16* __restrict__ wvb, bf16* __restrict__ wob, bf16* __restrict__ erb)
{
    const int r = blockIdx.y;
    const float* s; bf16* d; int n4;
    if      (r == 0) { s = x;  d = xb;  n4 = 1048576; }
    else if (r == 1) { s = wq; d = wqb; n4 = 262144;  }
    else if (r == 2) { s = wk; d = wkb; n4 = 262144;  }
    else if (r == 3) { s = wv; d = wvb; n4 = 262144;  }
    else if (r == 4) { s = wo; d = wob; n4 = 262144;  }
    else             { s = er; d = erb; n4 = 32768;   }
    const int i = blockIdx.x * 256 + threadIdx.x;
    if (i < n4) {
        const float4 v = ((const float4*)s)[i];
        bf16 t[4];
        t[0] = __float2bfloat16(v.x);
        t[1] = __float2bfloat16(v.y);
        t[2] = __float2bfloat16(v.z);
        t[3] = __float2bfloat16(v.w);
        ((uint2*)d)[i] = *(const uint2*)t;
    }
}

// ---------------------------------------------------------------------------
// NT GEMM: out = A @ W^T + bias.  M=4096, N=1024, K=1024.  128x128 tile.
// (unchanged — known-good)
// ---------------------------------------------------------------------------
__global__ __launch_bounds__(256) void gemm_nt(
    const bf16* __restrict__ A,
    const bf16* __restrict__ W0, const bf16* __restrict__ W1, const bf16* __restrict__ W2,
    const float* __restrict__ b0, const float* __restrict__ b1, const float* __restrict__ b2,
    bf16* __restrict__ o0, bf16* __restrict__ o1, bf16* __restrict__ o2,
    float* __restrict__ outf, int headmajor)
{
    const int z = blockIdx.z;
    const bf16* W     = (z == 0) ? W0 : (z == 1) ? W1 : W2;
    const float* bias = (z == 0) ? b0 : (z == 1) ? b1 : b2;
    bf16* out         = (z == 0) ? o0 : (z == 1) ? o1 : o2;

    __shared__ bf16 As[128 * 40];
    __shared__ bf16 Bs[128 * 40];

    const int tid = threadIdx.x;
    const int w  = tid >> 6, l = tid & 63;
    const int lm = l & 15,  lq = l >> 4;
    const int wm = (w >> 1) * 64, wn = (w & 1) * 64;
    const int m0 = blockIdx.y * 128, n0 = blockIdx.x * 128;

    v4f acc[4][4];
#pragma unroll
    for (int i = 0; i < 4; ++i)
#pragma unroll
        for (int j = 0; j < 4; ++j) acc[i][j] = (v4f){0.f, 0.f, 0.f, 0.f};

    const int r0 = tid >> 2;
    const int c8 = (tid & 3) * 8;

    for (int k0 = 0; k0 < 1024; k0 += 32) {
        __syncthreads();
#pragma unroll
        for (int rep = 0; rep < 2; ++rep) {
            const int row = r0 + rep * 64;
            *(uint4*)&As[row * 40 + c8] = *(const uint4*)&A[(size_t)(m0 + row) * 1024 + k0 + c8];
            *(uint4*)&Bs[row * 40 + c8] = *(const uint4*)&W[(size_t)(n0 + row) * 1024 + k0 + c8];
        }
        __syncthreads();
        v8s a[4], b[4];
#pragma unroll
        for (int i = 0; i < 4; ++i) a[i] = *(const v8s*)&As[(wm + i * 16 + lm) * 40 + lq * 8];
#pragma unroll
        for (int j = 0; j < 4; ++j) b[j] = *(const v8s*)&Bs[(wn + j * 16 + lm) * 40 + lq * 8];
#pragma unroll
        for (int i = 0; i < 4; ++i)
#pragma unroll
            for (int j = 0; j < 4; ++j)
                acc[i][j] = MFMA(a[i], b[j], acc[i][j]);
    }

    float bv[4];
#pragma unroll
    for (int j = 0; j < 4; ++j) bv[j] = bias[n0 + wn + j * 16 + lm];

#pragma unroll
    for (int i = 0; i < 4; ++i) {
#pragma unroll
        for (int j = 0; j < 4; ++j) {
            const int col = n0 + wn + j * 16 + lm;
#pragma unroll
            for (int r = 0; r < 4; ++r) {
                const int row = m0 + wm + i * 16 + lq * 4 + r;
                const float v = acc[i][j][r] + bv[j];
                if (headmajor) {
                    const int bb = row >> 11, ss = row & 2047;
                    const int hh = col >> 6,  dd = col & 63;
                    out[((size_t)(bb * 16 + hh) * 2048 + ss) * 64 + dd] = __float2bfloat16(v);
                } else {
                    outf[(size_t)row * 1024 + col] = v;
                }
            }
        }
    }
}

// ---------------------------------------------------------------------------
// V transpose: (b,h,s,d) -> (b,h,d,s).
// ---------------------------------------------------------------------------
__global__ __launch_bounds__(256) void vtrans(const bf16* __restrict__ V, bf16* __restrict__ Vt)
{
    __shared__ bf16 T[64 * 72];
    const int s0  = blockIdx.x * 64;
    const int bh  = blockIdx.y;
    const int tid = threadIdx.x;
#pragma unroll
    for (int rep = 0; rep < 2; ++rep) {
        const int unit = tid + rep * 256;
        const int sl = unit >> 3, d8 = (unit & 7) * 8;
        *(uint4*)&T[sl * 72 + d8] = *(const uint4*)&V[((size_t)bh * 2048 + s0 + sl) * 64 + d8];
    }
    __syncthreads();
#pragma unroll
    for (int rep = 0; rep < 2; ++rep) {
        const int unit = tid + rep * 256;
        const int d = unit >> 3, t8 = (unit & 7) * 8;
        unsigned short tmp[8];
#pragma unroll
        for (int j = 0; j < 8; ++j) tmp[j] = *(const unsigned short*)&T[(t8 + j) * 72 + d];
        *(uint4*)&Vt[((size_t)bh * 64 + d) * 2048 + s0 + t8] = *(const uint4*)tmp;
    }
}

// ---------------------------------------------------------------------------
// Flash attention + skewed rel-pos bias, v4: flat balanced split-K schedule.
// Max-free softmax (P = exp(s-4), fixed shift) makes partials ADDITIVE:
// O-partials and denominators from disjoint KV ranges combine by pure
// addition — no rescale, no merge logic. So we flatten all
// sum_{qb}(qb+1)*32bh = 16896 KV-tile iterations into a global work list and
// give every block exactly 16 or 17 consecutive items (alternating; any 4
// consecutive blocks carry 66 iters). This removes the qb+1-iteration
// imbalance that capped the old makespan at the LONGEST resident block
// (~32 iters vs 16.5 avg -> Occupancy 26% of a 50% ceiling).
// Sole owners of a (bh,qb) tile do plain stores; split segments atomicAdd
// into the zeroed fp32 scratch (d_out, dead until final GEMM). A normalize
// kernel divides by the denominator and casts to bf16.
// Inner-loop body is unchanged from v3.
// ---------------------------------------------------------------------------
__global__ __launch_bounds__(256, 4) void attn(
    const bf16* __restrict__ Q, const bf16* __restrict__ K,
    const bf16* __restrict__ Vt, const bf16* __restrict__ Er,
    float* __restrict__ Of, float* __restrict__ dsum)
{
    __shared__ bf16 Ks[64 * 72];
    __shared__ bf16 Vs[64 * 72];
    __shared__ bf16 Ps[64 * 72];
    __shared__ bf16 Gs[64 * 84];   // [wave*16+rl][80 used], bf16, pre-scaled

    const int tid = threadIdx.x;
    const int w  = tid >> 6, l = tid & 63;
    const int lm = l & 15,  lq = l >> 4;
    const int sr0 = tid >> 3;          // 0..31 (+32 on rep1)
    const int sc8 = (tid & 7) * 8;

    // flat work range: item g -> (bh = g/528, triangular rem -> (qb, kv-tile))
    const int ord = blockIdx.x;
    int g = ord * 16 + ((ord + 1) >> 1);          // alternating 17/16 items
    const int gend = g + ((ord & 1) ? 16 : 17);

    while (g < gend) {
        const int bh  = g / 528;
        const int rem = g - bh * 528;
        int qb = (int)((sqrtf(8.f * (float)rem + 1.f) - 1.f) * 0.5f);
        while ((qb + 1) * (qb + 2) / 2 <= rem) ++qb;   // exact fixup
        while (qb * (qb + 1) / 2 > rem) --qb;
        const int t0 = rem - (qb * (qb + 1)) / 2;      // first kv tile
        int nt = qb + 1 - t0;                          // tiles in this segment
        if (nt > gend - g) nt = gend - g;

        const int i0 = qb * 64;
        const int b  = bh >> 4, h = bh & 15;

        const bf16* qp = Q + ((size_t)bh * 2048 + i0 + w * 16 + lm) * 64 + lq * 8;
        const v8s q0  = *(const v8s*)qp;
        const v8s q1f = *(const v8s*)(qp + 32);

        v4f accO[4];
#pragma unroll
        for (int dt = 0; dt < 4; ++dt) accO[dt] = (v4f){0.f, 0.f, 0.f, 0.f};
        float rs[4] = {0.f, 0.f, 0.f, 0.f};

        const size_t kbase = (size_t)bh * 2048 * 64;
        const size_t vbase = (size_t)bh * 64 * 2048;
        const int jt0 = t0 * 64;

        // prefetch first tile of segment
        uint4 kp0 = *(const uint4*)&K[kbase + (size_t)(jt0 + sr0) * 64 + sc8];
        uint4 kp1 = *(const uint4*)&K[kbase + (size_t)(jt0 + sr0 + 32) * 64 + sc8];
        uint4 vp0 = *(const uint4*)&Vt[vbase + (size_t)sr0 * 2048 + jt0 + sc8];
        uint4 vp1 = *(const uint4*)&Vt[vbase + (size_t)(sr0 + 32) * 2048 + jt0 + sc8];

        for (int tt = 0; tt < nt; ++tt) {
            const int jt = jt0 + tt * 64;
            __syncthreads();                       // prev iter's LDS reads done
            *(uint4*)&Ks[sr0 * 72 + sc8]        = kp0;
            *(uint4*)&Ks[(sr0 + 32) * 72 + sc8] = kp1;
            *(uint4*)&Vs[sr0 * 72 + sc8]        = vp0;
            *(uint4*)&Vs[(sr0 + 32) * 72 + sc8] = vp1;
            if (tt + 1 < nt) {                     // prefetch next tile
                const int jn = jt + 64;
                kp0 = *(const uint4*)&K[kbase + (size_t)(jn + sr0) * 64 + sc8];
                kp1 = *(const uint4*)&K[kbase + (size_t)(jn + sr0 + 32) * 64 + sc8];
                vp0 = *(const uint4*)&Vt[vbase + (size_t)sr0 * 2048 + jn + sc8];
                vp1 = *(const uint4*)&Vt[vbase + (size_t)(sr0 + 32) * 2048 + jn + sc8];
            }
            // G band: wave-local base; 5 column-tiles of 16 cover the 79 needed
            const int basew = 2048 - 16 - i0 + jt - 16 * w;
#pragma unroll
            for (int ct2 = 0; ct2 < 5; ++ct2) {
                int mr = basew + ct2 * 16 + lm;
                mr = (mr > 2047) ? 2047 : mr;      // clamped rows feed masked cols only
                const bf16* ep = Er + (size_t)mr * 64 + lq * 8;
                const v8s e0 = *(const v8s*)ep;
                const v8s e1 = *(const v8s*)(ep + 32);
                v4f gg = (v4f){0.f, 0.f, 0.f, 0.f};
                gg = MFMA(q0, e0, gg);
                gg = MFMA(q1f, e1, gg);
#pragma unroll
                for (int r = 0; r < 4; ++r)
                    Gs[(w * 16 + lq * 4 + r) * 84 + ct2 * 16 + lm] =
                        __float2bfloat16(gg[r] * 0.125f);
            }
            __syncthreads();                       // K/V staged, visible
            // QK^T for this wave's 16-row stripe
            v4f sv[4];
#pragma unroll
            for (int ct = 0; ct < 4; ++ct) {
                const v8s k0f = *(const v8s*)&Ks[(ct * 16 + lm) * 72 + lq * 8];
                const v8s k1f = *(const v8s*)&Ks[(ct * 16 + lm) * 72 + 32 + lq * 8];
                v4f s = (v4f){0.f, 0.f, 0.f, 0.f};
                s = MFMA(q0, k0f, s);
                s = MFMA(q1f, k1f, s);
                sv[ct] = s;
            }
            // scores + rel gather + mask + exp (no cross-lane work in the loop)
#pragma unroll
            for (int r = 0; r < 4; ++r) {
                const int rl = lq * 4 + r;
                const int ig = i0 + w * 16 + rl;
#pragma unroll
                for (int ct = 0; ct < 4; ++ct) {
                    const int jj = ct * 16 + lm;
                    const float gb = (float)Gs[(w * 16 + rl) * 84 + jj + 15 - rl];
                    float s = fmaf(sv[ct][r], 0.125f, gb);
                    if (jt + jj > ig) s = -1e9f;
                    const float pe = __expf(s - 4.0f);
                    rs[r] += pe;
                    Ps[(w * 16 + rl) * 72 + jj] = __float2bfloat16(pe);
                }
            }
            // PV
            const v8s pa0 = *(const v8s*)&Ps[(w * 16 + lm) * 72 + lq * 8];
            const v8s pa1 = *(const v8s*)&Ps[(w * 16 + lm) * 72 + 32 + lq * 8];
#pragma unroll
            for (int dt = 0; dt < 4; ++dt) {
                const v8s vb0 = *(const v8s*)&Vs[(dt * 16 + lm) * 72 + lq * 8];
                const v8s vb1 = *(const v8s*)&Vs[(dt * 16 + lm) * 72 + 32 + lq * 8];
                accO[dt] = MFMA(pa0, vb0, accO[dt]);
                accO[dt] = MFMA(pa1, vb1, accO[dt]);
            }
        }
        // segment epilogue: reduce denominator over 16 lm lanes, emit partials
#pragma unroll
        for (int r = 0; r < 4; ++r) {
#pragma unroll
            for (int msk = 8; msk >= 1; msk >>= 1)
                rs[r] += __shfl_xor(rs[r], msk, 64);
        }
        const bool full = (t0 == 0) && (nt == qb + 1);   // sole owner of (bh,qb)
#pragma unroll
        for (int dt = 0; dt < 4; ++dt) {
#pragma unroll
            for (int r = 0; r < 4; ++r) {
                const int row = i0 + w * 16 + lq * 4 + r;
                const int d   = dt * 16 + lm;
                const size_t idx = ((size_t)b * 2048 + row) * 1024 + h * 64 + d;
                if (full) Of[idx] = accO[dt][r];
                else      atomicAdd(&Of[idx], accO[dt][r]);
            }
        }
        if (lm == 0) {
#pragma unroll
            for (int r = 0; r < 4; ++r) {
                const int row = i0 + w * 16 + lq * 4 + r;
                if (full) dsum[bh * 2048 + row] = rs[r];
                else      atomicAdd(&dsum[bh * 2048 + row], rs[r]);
            }
        }
        g += nt;
    }
}

// ---------------------------------------------------------------------------
// normalize: AO = bf16(Of / dsum[row]).  1,048,576 float4s.
// ---------------------------------------------------------------------------
__global__ __launch_bounds__(256) void normalize(
    const float* __restrict__ Of, const float* __restrict__ dsum,
    bf16* __restrict__ AO)
{
    const int i = blockIdx.x * 256 + threadIdx.x;   // float4 index
    const float4 v = ((const float4*)Of)[i];
    const int e   = i * 4;
    const int row = e >> 10;                        // b*2048+s, 0..4095
    const int hh  = (e >> 6) & 15;
    const int bb  = row >> 11, ss = row & 2047;
    const float inv = 1.0f / dsum[(size_t)(bb * 16 + hh) * 2048 + ss];
    bf16 t[4];
    t[0] = __float2bfloat16(v.x * inv);
    t[1] = __float2bfloat16(v.y * inv);
    t[2] = __float2bfloat16(v.z * inv);
    t[3] = __float2bfloat16(v.w * inv);
    ((uint2*)AO)[i] = *(const uint2*)t;
}

// ---------------------------------------------------------------------------
extern "C" void kernel_launch(void* const* d_in, const int* in_sizes, int n_in,
                              void* d_out, int out_size, void* d_ws, size_t ws_size,
                              hipStream_t stream)
{
    const float* x  = (const float*)d_in[0];
    const float* Wq = (const float*)d_in[1];
    const float* bq = (const float*)d_in[2];
    const float* Wk = (const float*)d_in[3];
    const float* bk = (const float*)d_in[4];
    const float* Wv = (const float*)d_in[5];
    const float* bv = (const float*)d_in[6];
    const float* Er = (const float*)d_in[7];
    const float* Wo = (const float*)d_in[8];
    const float* bo = (const float*)d_in[9];
    float* out = (float*)d_out;

    bf16* ws = (bf16*)d_ws;
    const size_t NEl = (size_t)4096 * 1024;
    bf16* Qw  = ws;                 // (b,h,s,d)
    bf16* Kw  = ws + NEl;           // (b,h,s,d)
    bf16* Vw  = ws + 2 * NEl;       // (b,h,s,d)
    bf16* Vtw = ws + 3 * NEl;       // (b,h,d,s)
    bf16* xb  = ws + 4 * NEl;       // bf16 x; dead after gemm1
    bf16* AOw = xb;                 // aliased
    bf16* Wqb = ws + 5 * NEl;
    bf16* Wkb = Wqb + 1024 * 1024;
    bf16* Wvb = Wkb + 1024 * 1024;
    bf16* Wob = Wvb + 1024 * 1024;
    bf16* Erb = Wob + 1024 * 1024;
    float* dsumf = (float*)(Erb + (size_t)2048 * 64);   // 32*2048 fp32 = 256 KB

    // zero split-K accumulators: d_out doubles as fp32 O-partial scratch
    // (dead until the final GEMM overwrites it)
    hipMemsetAsync(out,   0, NEl * sizeof(float), stream);
    hipMemsetAsync(dsumf, 0, (size_t)32 * 2048 * sizeof(float), stream);

    cast_all<<<dim3(4096, 6), 256, 0, stream>>>(x, Wq, Wk, Wv, Wo, Er,
                                                xb, Wqb, Wkb, Wvb, Wob, Erb);
    gemm_nt<<<dim3(8, 32, 3), 256, 0, stream>>>(xb, Wqb, Wkb, Wvb, bq, bk, bv,
                                                Qw, Kw, Vw, nullptr, 1);
    vtrans<<<dim3(32, 32), 256, 0, stream>>>(Vw, Vtw);
    attn<<<dim3(1024), 256, 0, stream>>>(Qw, Kw, Vtw, Erb, out, dsumf);
    normalize<<<dim3(4096), 256, 0, stream>>>(out, dsumf, AOw);
    gemm_nt<<<dim3(8, 32, 1), 256, 0, stream>>>(AOw, Wob, Wob, Wob, bo, bo, bo,
                                                AOw, AOw, AOw, out, 0);
}

// Round 2
// 278.327 us; speedup vs baseline: 1.0880x; 1.0880x over previous
//
#include <hip/hip_runtime.h>
#include <hip/hip_bf16.h>

typedef short v8s __attribute__((ext_vector_type(8)));
typedef float v4f __attribute__((ext_vector_type(4)));
typedef __hip_bfloat16 bf16;
typedef unsigned int u32;

#define MFMA(a, b, c) __builtin_amdgcn_mfma_f32_16x16x32_bf16(a, b, c, 0, 0, 0)

// direct global->LDS DMA, 16B per lane. LDS dest = wave-uniform base + lane*16.
__device__ __forceinline__ void gload16(const bf16* g, bf16* l) {
    __builtin_amdgcn_global_load_lds(
        (const __attribute__((address_space(1))) u32*)(g),
        (__attribute__((address_space(3))) u32*)(l), 16, 0, 0);
}

// ---------------------------------------------------------------------------
// All fp32->bf16 casts in ONE launch. grid=(4096,6); region r sized n4 vec4s.
// ---------------------------------------------------------------------------
__global__ __launch_bounds__(256) void cast_all(
    const float* __restrict__ x,  const float* __restrict__ wq,
    const float* __restrict__ wk, const float* __restrict__ wv,
    const float* __restrict__ wo, const float* __restrict__ er,
    bf16* __restrict__ xb,  bf16* __restrict__ wqb, bf16* __restrict__ wkb,
    bf16* __restrict__ wvb, bf16* __restrict__ wob, bf16* __restrict__ erb)
{
    const int r = blockIdx.y;
    const float* s; bf16* d; int n4;
    if      (r == 0) { s = x;  d = xb;  n4 = 1048576; }
    else if (r == 1) { s = wq; d = wqb; n4 = 262144;  }
    else if (r == 2) { s = wk; d = wkb; n4 = 262144;  }
    else if (r == 3) { s = wv; d = wvb; n4 = 262144;  }
    else if (r == 4) { s = wo; d = wob; n4 = 262144;  }
    else             { s = er; d = erb; n4 = 32768;   }
    const int i = blockIdx.x * 256 + threadIdx.x;
    if (i < n4) {
        const float4 v = ((const float4*)s)[i];
        bf16 t[4];
        t[0] = __float2bfloat16(v.x);
        t[1] = __float2bfloat16(v.y);
        t[2] = __float2bfloat16(v.z);
        t[3] = __float2bfloat16(v.w);
        ((uint2*)d)[i] = *(const uint2*)t;
    }
}

// ---------------------------------------------------------------------------
// NT GEMM v2: out = A @ Wcat^T + bias, Wcat rows = concatenated weights.
//  - 128x128 tile, BK=64, single-buffer 2-barrier (m97 structure)
//  - global_load_lds width=16 staging (ladder step 3: +69% over VGPR roundtrip)
//  - linear LDS + XOR swizzle, BOTH sides (rule #21): source lane col16 is
//    pre-swizzled by row&7, ds_read applies the same involution -> 8-way
//    conflict instead of 16-way padless, and DMA stays legal.
// QKV fused: grid.x covers N=3072 (Wq|Wk|Wv contiguous); z = blockIdx.x>>3
// selects bias + headmajor output slab. Proj: grid.x=8 -> z=0, fp32 rowmajor.
// ---------------------------------------------------------------------------
__global__ __launch_bounds__(256) void gemm_nt(
    const bf16* __restrict__ A, const bf16* __restrict__ W,
    const float* __restrict__ b0, const float* __restrict__ b1,
    const float* __restrict__ b2,
    bf16* __restrict__ oHM, float* __restrict__ outf)
{
    __shared__ bf16 As[128 * 64];
    __shared__ bf16 Bs[128 * 64];

    const int tid = threadIdx.x;
    const int w  = tid >> 6, l = tid & 63;
    const int lm = l & 15,  lq = l >> 4;
    const int wm = (w >> 1) * 64, wn = (w & 1) * 64;
    const int m0 = blockIdx.y * 128, n0 = blockIdx.x * 128;

    // staging lane map: instr q covers rows w*32+q*8+(l>>3); source column is
    // pre-swizzled so that linear LDS + swizzled read see the right element.
    const int grow = l >> 3;                       // 0..7, == row&7 (q*8 kills bit 0-2)
    const int gcol = ((l & 7) ^ grow) * 8;         // bf16 units, 16B granules

    v4f acc[4][4];
#pragma unroll
    for (int i = 0; i < 4; ++i)
#pragma unroll
        for (int j = 0; j < 4; ++j) acc[i][j] = (v4f){0.f, 0.f, 0.f, 0.f};

    // read-side swizzled byte offsets (row&7 == lm&7 for all fragment rows)
    const int sw = (lm & 7) << 4;

    for (int k0 = 0; k0 < 1024; k0 += 64) {
        __syncthreads();                           // LDS reuse guard
#pragma unroll
        for (int q = 0; q < 4; ++q) {
            const int rr = w * 32 + q * 8;
            gload16(&A[(size_t)(m0 + rr + grow) * 1024 + k0 + gcol], &As[rr * 64]);
            gload16(&W[(size_t)(n0 + rr + grow) * 1024 + k0 + gcol], &Bs[rr * 64]);
        }
        __syncthreads();                           // vmcnt drained at barrier
#pragma unroll
        for (int kk = 0; kk < 2; ++kk) {
            v8s a[4], b[4];
            const int cb = (lq * 16 + kk * 64);
#pragma unroll
            for (int i = 0; i < 4; ++i) {
                const int row = wm + i * 16 + lm;
                a[i] = *(const v8s*)((const char*)As + row * 128 + (cb ^ sw));
            }
#pragma unroll
            for (int j = 0; j < 4; ++j) {
                const int row = wn + j * 16 + lm;
                b[j] = *(const v8s*)((const char*)Bs + row * 128 + (cb ^ sw));
            }
#pragma unroll
            for (int i = 0; i < 4; ++i)
#pragma unroll
                for (int j = 0; j < 4; ++j)
                    acc[i][j] = MFMA(a[i], b[j], acc[i][j]);
        }
    }

    const int z = blockIdx.x >> 3;                 // 1024-col slab
    const float* bias = (z == 0) ? b0 : (z == 1) ? b1 : b2;

    float bv[4];
#pragma unroll
    for (int j = 0; j < 4; ++j) bv[j] = bias[(n0 & 1023) + wn + j * 16 + lm];

#pragma unroll
    for (int i = 0; i < 4; ++i) {
#pragma unroll
        for (int j = 0; j < 4; ++j) {
            const int col = n0 + wn + j * 16 + lm;
            const int cc  = col & 1023;
#pragma unroll
            for (int r = 0; r < 4; ++r) {
                const int row = m0 + wm + i * 16 + lq * 4 + r;
                const float v = acc[i][j][r] + bv[j];
                if (outf) {
                    outf[(size_t)row * 1024 + cc] = v;
                } else {
                    const int bb = row >> 11, ss = row & 2047;
                    const int hh = cc >> 6,  dd = cc & 63;
                    oHM[(size_t)z * 4194304 +
                        ((size_t)(bb * 16 + hh) * 2048 + ss) * 64 + dd] = __float2bfloat16(v);
                }
            }
        }
    }
}

// ---------------------------------------------------------------------------
// V transpose: (b,h,s,d) -> (b,h,d,s).
// ---------------------------------------------------------------------------
__global__ __launch_bounds__(256) void vtrans(const bf16* __restrict__ V, bf16* __restrict__ Vt)
{
    __shared__ bf16 T[64 * 72];
    const int s0  = blockIdx.x * 64;
    const int bh  = blockIdx.y;
    const int tid = threadIdx.x;
#pragma unroll
    for (int rep = 0; rep < 2; ++rep) {
        const int unit = tid + rep * 256;
        const int sl = unit >> 3, d8 = (unit & 7) * 8;
        *(uint4*)&T[sl * 72 + d8] = *(const uint4*)&V[((size_t)bh * 2048 + s0 + sl) * 64 + d8];
    }
    __syncthreads();
#pragma unroll
    for (int rep = 0; rep < 2; ++rep) {
        const int unit = tid + rep * 256;
        const int d = unit >> 3, t8 = (unit & 7) * 8;
        unsigned short tmp[8];
#pragma unroll
        for (int j = 0; j < 8; ++j) tmp[j] = *(const unsigned short*)&T[(t8 + j) * 72 + d];
        *(uint4*)&Vt[((size_t)bh * 64 + d) * 2048 + s0 + t8] = *(const uint4*)tmp;
    }
}

// ---------------------------------------------------------------------------
// Flash attention + skewed rel-pos bias, v3 (known-good, 122 us): max-free
// softmax P=exp(s-4), fixed shift; per-lane denominator, single epilogue
// reduce; register prefetch of next K/V tile; balanced qb schedule.
// (v4 flat split-K REGRESSED: balance gain < partial-traffic + L2 loss.)
// ---------------------------------------------------------------------------
__global__ __launch_bounds__(256, 4) void attn(
    const bf16* __restrict__ Q, const bf16* __restrict__ K,
    const bf16* __restrict__ Vt, const bf16* __restrict__ Er,
    bf16* __restrict__ AO)
{
    __shared__ bf16 Ks[64 * 72];
    __shared__ bf16 Vs[64 * 72];
    __shared__ bf16 Ps[64 * 72];
    __shared__ bf16 Gs[64 * 84];   // [wave*16+rl][80 used], bf16, pre-scaled

    // balanced schedule (1-D grid of 1024): CU's 4 blocks sum to 66 iters
    const int ord = blockIdx.x;
    const int u = ord & 255, j = ord >> 8;
    const int a = u & 31, yh = u >> 5;
    const int q1 = (j & 2) ? (a ^ 16) : a;
    const int qb = (j & 1) ? (31 - q1) : q1;
    const int bh = 8 * j + yh;

    const int i0 = qb * 64;
    const int b  = bh >> 4, h = bh & 15;
    const int tid = threadIdx.x;
    const int w  = tid >> 6, l = tid & 63;
    const int lm = l & 15,  lq = l >> 4;

    const bf16* qp = Q + ((size_t)bh * 2048 + i0 + w * 16 + lm) * 64 + lq * 8;
    const v8s q0 = *(const v8s*)qp;
    const v8s q1f = *(const v8s*)(qp + 32);

    v4f accO[4];
#pragma unroll
    for (int dt = 0; dt < 4; ++dt) accO[dt] = (v4f){0.f, 0.f, 0.f, 0.f};
    float rs[4];
#pragma unroll
    for (int r = 0; r < 4; ++r) rs[r] = 0.f;

    const int sr0 = tid >> 3;          // 0..31 (+32 on rep1)
    const int sc8 = (tid & 7) * 8;
    const size_t kbase = (size_t)bh * 2048 * 64;
    const size_t vbase = (size_t)bh * 64 * 2048;

    const int nk = qb + 1;

    // prefetch tile 0
    uint4 kp0 = *(const uint4*)&K[kbase + (size_t)sr0 * 64 + sc8];
    uint4 kp1 = *(const uint4*)&K[kbase + (size_t)(sr0 + 32) * 64 + sc8];
    uint4 vp0 = *(const uint4*)&Vt[vbase + (size_t)sr0 * 2048 + sc8];
    uint4 vp1 = *(const uint4*)&Vt[vbase + (size_t)(sr0 + 32) * 2048 + sc8];

    for (int it = 0; it < nk; ++it) {
        const int j0 = it * 64;
        __syncthreads();                       // prev iter's LDS reads done
        *(uint4*)&Ks[sr0 * 72 + sc8]        = kp0;
        *(uint4*)&Ks[(sr0 + 32) * 72 + sc8] = kp1;
        *(uint4*)&Vs[sr0 * 72 + sc8]        = vp0;
        *(uint4*)&Vs[(sr0 + 32) * 72 + sc8] = vp1;
        if (it + 1 < nk) {                     // prefetch next tile
            const int jn = j0 + 64;
            kp0 = *(const uint4*)&K[kbase + (size_t)(jn + sr0) * 64 + sc8];
            kp1 = *(const uint4*)&K[kbase + (size_t)(jn + sr0 + 32) * 64 + sc8];
            vp0 = *(const uint4*)&Vt[vbase + (size_t)sr0 * 2048 + jn + sc8];
            vp1 = *(const uint4*)&Vt[vbase + (size_t)(sr0 + 32) * 2048 + jn + sc8];
        }
        // G band: wave-local base; 5 column-tiles of 16 cover the 79 needed
        const int basew = 2048 - 16 - i0 + j0 - 16 * w;
#pragma unroll
        for (int ct2 = 0; ct2 < 5; ++ct2) {
            int mr = basew + ct2 * 16 + lm;
            mr = (mr > 2047) ? 2047 : mr;      // clamped rows feed masked cols only
            const bf16* ep = Er + (size_t)mr * 64 + lq * 8;
            const v8s e0 = *(const v8s*)ep;
            const v8s e1 = *(const v8s*)(ep + 32);
            v4f g = (v4f){0.f, 0.f, 0.f, 0.f};
            g = MFMA(q0, e0, g);
            g = MFMA(q1f, e1, g);
#pragma unroll
            for (int r = 0; r < 4; ++r)
                Gs[(w * 16 + lq * 4 + r) * 84 + ct2 * 16 + lm] =
                    __float2bfloat16(g[r] * 0.125f);
        }
        __syncthreads();                       // K/V staged, visible
        // QK^T for this wave's 16-row stripe
        v4f sv[4];
#pragma unroll
        for (int ct = 0; ct < 4; ++ct) {
            const v8s k0f = *(const v8s*)&Ks[(ct * 16 + lm) * 72 + lq * 8];
            const v8s k1f = *(const v8s*)&Ks[(ct * 16 + lm) * 72 + 32 + lq * 8];
            v4f s = (v4f){0.f, 0.f, 0.f, 0.f};
            s = MFMA(q0, k0f, s);
            s = MFMA(q1f, k1f, s);
            sv[ct] = s;
        }
        // scores + rel gather + mask + exp (no cross-lane work in the loop)
#pragma unroll
        for (int r = 0; r < 4; ++r) {
            const int rl = lq * 4 + r;
            const int ig = i0 + w * 16 + rl;
#pragma unroll
            for (int ct = 0; ct < 4; ++ct) {
                const int jj = ct * 16 + lm;
                const float gb = (float)Gs[(w * 16 + rl) * 84 + jj + 15 - rl];
                float s = fmaf(sv[ct][r], 0.125f, gb);
                if (j0 + jj > ig) s = -1e9f;
                const float pe = __expf(s - 4.0f);
                rs[r] += pe;
                Ps[(w * 16 + rl) * 72 + jj] = __float2bfloat16(pe);
            }
        }
        // PV
        const v8s pa0 = *(const v8s*)&Ps[(w * 16 + lm) * 72 + lq * 8];
        const v8s pa1 = *(const v8s*)&Ps[(w * 16 + lm) * 72 + 32 + lq * 8];
#pragma unroll
        for (int dt = 0; dt < 4; ++dt) {
            const v8s vb0 = *(const v8s*)&Vs[(dt * 16 + lm) * 72 + lq * 8];
            const v8s vb1 = *(const v8s*)&Vs[(dt * 16 + lm) * 72 + 32 + lq * 8];
            accO[dt] = MFMA(pa0, vb0, accO[dt]);
            accO[dt] = MFMA(pa1, vb1, accO[dt]);
        }
    }
    // epilogue: the ONLY cross-lane reduction (denominator over 16 lm lanes)
#pragma unroll
    for (int r = 0; r < 4; ++r) {
#pragma unroll
        for (int msk = 8; msk >= 1; msk >>= 1)
            rs[r] += __shfl_xor(rs[r], msk, 64);
    }
#pragma unroll
    for (int dt = 0; dt < 4; ++dt) {
#pragma unroll
        for (int r = 0; r < 4; ++r) {
            const int row = i0 + w * 16 + lq * 4 + r;
            const int d   = dt * 16 + lm;
            const float v = accO[dt][r] / rs[r];
            AO[((size_t)b * 2048 + row) * 1024 + h * 64 + d] = __float2bfloat16(v);
        }
    }
}

// ---------------------------------------------------------------------------
extern "C" void kernel_launch(void* const* d_in, const int* in_sizes, int n_in,
                              void* d_out, int out_size, void* d_ws, size_t ws_size,
                              hipStream_t stream)
{
    const float* x  = (const float*)d_in[0];
    const float* Wq = (const float*)d_in[1];
    const float* bq = (const float*)d_in[2];
    const float* Wk = (const float*)d_in[3];
    const float* bk = (const float*)d_in[4];
    const float* Wv = (const float*)d_in[5];
    const float* bv = (const float*)d_in[6];
    const float* Er = (const float*)d_in[7];
    const float* Wo = (const float*)d_in[8];
    const float* bo = (const float*)d_in[9];
    float* out = (float*)d_out;

    bf16* ws = (bf16*)d_ws;
    const size_t NEl = (size_t)4096 * 1024;
    bf16* Qw  = ws;                 // (b,h,s,d); Kw, Vw follow contiguously
    bf16* Kw  = ws + NEl;
    bf16* Vw  = ws + 2 * NEl;
    bf16* Vtw = ws + 3 * NEl;       // (b,h,d,s)
    bf16* xb  = ws + 4 * NEl;       // bf16 x; dead after QKV gemm
    bf16* AOw = xb;                 // aliased
    bf16* Wqb = ws + 5 * NEl;       // Wq|Wk|Wv contiguous -> one N=3072 GEMM
    bf16* Wkb = Wqb + 1024 * 1024;
    bf16* Wvb = Wkb + 1024 * 1024;
    bf16* Wob = Wvb + 1024 * 1024;
    bf16* Erb = Wob + 1024 * 1024;
    (void)Kw; (void)Vw; (void)Wkb; (void)Wvb;

    cast_all<<<dim3(4096, 6), 256, 0, stream>>>(x, Wq, Wk, Wv, Wo, Er,
                                                xb, Wqb, Wkb, Wvb, Wob, Erb);
    // fused QKV: N=3072 over contiguous Wq|Wk|Wv, headmajor bf16 out
    gemm_nt<<<dim3(24, 32), 256, 0, stream>>>(xb, Wqb, bq, bk, bv, Qw, nullptr);
    vtrans<<<dim3(32, 32), 256, 0, stream>>>(Vw, Vtw);
    attn<<<dim3(1024), 256, 0, stream>>>(Qw, Kw, Vtw, Erb, AOw);
    // output projection: N=1024, fp32 rowmajor into d_out
    gemm_nt<<<dim3(8, 32), 256, 0, stream>>>(AOw, Wob, bo, bo, bo, nullptr, out);
}